// Round 8
// baseline (3153.543 us; speedup 1.0000x reference)
//
#include <hip/hip_runtime.h>

#define TT 512
#define BB 64
#define EE 256
#define HH 200
#define GG 800
#define CC 20
#define MM (BB * TT)  // 32768 tokens

// Collision-proof names (HIP's hip_vector_types.h defines short8/float8/etc).
typedef _Float16 f16x8 __attribute__((ext_vector_type(8)));
typedef float    f32x4 __attribute__((ext_vector_type(4)));
typedef _Float16 f16x2 __attribute__((ext_vector_type(2)));
typedef int      i32x4 __attribute__((ext_vector_type(4)));

#if __has_builtin(__builtin_amdgcn_mfma_f32_16x16x32_f16)
#define HAVE_MFMA_F16 1
#else
#define HAVE_MFMA_F16 0
#endif

__device__ __forceinline__ float bf2f(unsigned short u) {
  return __uint_as_float(((unsigned int)u) << 16);
}
__device__ __forceinline__ unsigned short f2bf(float f) {
  unsigned int u = __float_as_uint(f);
  return (unsigned short)((u + 0x7fffu + ((u >> 16) & 1u)) >> 16);
}
__device__ __forceinline__ float sigf(float x) { return 1.0f / (1.0f + __expf(-x)); }
__device__ __forceinline__ float tanhfast(float x) {
  return 1.0f - 2.0f / (__expf(2.0f * x) + 1.0f);
}
__device__ __forceinline__ f16x2 i2h2(int i) {
  union { int i; f16x2 h; } u; u.i = i; return u.h;
}
__device__ __forceinline__ float dot2acc(f16x2 a, f16x2 b, float c) {
#if __has_builtin(__builtin_amdgcn_fdot2)
  return __builtin_amdgcn_fdot2(a, b, c, false);
#else
  return c + (float)a[0] * (float)b[0] + (float)a[1] * (float)b[1];
#endif
}

// --------------------------------------------------- input dtype normalizer
// Emits, besides the bf16 copies, three f16 views of W_hh for k_lstm:
//   whh16 plain [2][800][200]           (register rows 0..255, direct f16 load)
//   ldsT  [2][25][384][8]  rows 256..639 (chunk-transposed: coalesced LDS fill,
//                                         conflict-free ds_read_b128)
//   strT  [2][25][160][8]  rows 640..799 (chunk-transposed: coalesced L2 stream)
#define NSEG 14
struct CvtArgs { const void* src[NSEG]; };
__constant__ const int cvt_cum[NSEG + 1] = {
    0, 8192000, 8192256, 8192512, 8397312, 8557312, 8558112,
    8762912, 8922912, 8923712, 8931712, 8931732, 8932132, 8932152, 8932172};

__global__ __launch_bounds__(256) void k_convert(CvtArgs a,
                                                 unsigned short* __restrict__ dst,
                                                 _Float16* __restrict__ whh16) {
  const bool f32mode = (((const unsigned int*)a.src[1])[0] == 0x3F800000u);
  int gi0 = (blockIdx.x * 256 + threadIdx.x) * 4;
#pragma unroll
  for (int r = 0; r < 4; ++r) {
    int gi = gi0 + r;
    if (gi >= cvt_cum[NSEG]) return;
    int seg = 0;
#pragma unroll
    for (int s = 1; s < NSEG; ++s) seg += (gi >= cvt_cum[s]) ? 1 : 0;
    int local = gi - cvt_cum[seg];
    unsigned short v;
    if (f32mode) v = f2bf(((const float*)a.src[seg])[local]);
    else         v = ((const unsigned short*)a.src[seg])[local];
    dst[gi] = v;
    if (seg == 4 || seg == 7) {
      int dir = (seg == 7) ? 1 : 0;
      int row = local / 200, col = local - row * 200;
      _Float16 hv = (_Float16)bf2f(v);
      whh16[dir * 160000 + local] = hv;
      if (row >= 256 && row < 640) {
        whh16[320000 + dir * 76800 + (col >> 3) * 3072 + (row - 256) * 8 + (col & 7)] = hv;
      } else if (row >= 640) {
        whh16[473600 + dir * 32000 + (col >> 3) * 1280 + (row - 640) * 8 + (col & 7)] = hv;
      }
    }
  }
}

// ---------------------------------------------------------------- embed + LN
__global__ __launch_bounds__(256) void k_embed_ln(
    const int* __restrict__ words, const unsigned short* __restrict__ etab,
    const unsigned short* __restrict__ gamma, const unsigned short* __restrict__ beta,
    unsigned short* __restrict__ x) {
  int m = blockIdx.x;      // token = b*TT + t
  int e = threadIdx.x;     // 0..255
  int w = words[m];
  float v = bf2f(etab[(size_t)w * EE + e]);
  float s = v, ss = v * v;
#pragma unroll
  for (int off = 32; off > 0; off >>= 1) {
    s += __shfl_xor(s, off, 64);
    ss += __shfl_xor(ss, off, 64);
  }
  __shared__ float red[2][4];
  int wv = e >> 6;
  if ((e & 63) == 0) { red[0][wv] = s; red[1][wv] = ss; }
  __syncthreads();
  float S = red[0][0] + red[0][1] + red[0][2] + red[0][3];
  float SS = red[1][0] + red[1][1] + red[1][2] + red[1][3];
  float mu = S * (1.0f / EE);
  float var = fmaxf(SS * (1.0f / EE) - mu * mu, 0.0f);
  float nrm = (v - mu) * rsqrtf(var + 1e-5f) * bf2f(gamma[e]) + bf2f(beta[e]);
  x[(size_t)m * EE + e] = f2bf(nrm);
}

// ------------------------------------------- gates_x = x @ W_ih^T + b
#if HAVE_MFMA_F16
__global__ __launch_bounds__(256) void k_gates(
    const unsigned short* __restrict__ x,
    const unsigned short* __restrict__ wih_f, const unsigned short* __restrict__ wih_b,
    const unsigned short* __restrict__ bias_f, const unsigned short* __restrict__ bias_b,
    unsigned short* __restrict__ gates) {
  const int dir = blockIdx.z;
  const unsigned short* wih = dir ? wih_b : wih_f;
  const unsigned short* bias = dir ? bias_b : bias_f;
  const int m0 = blockIdx.x * 64;
  const int n0 = blockIdx.y * 64;
  __shared__ __align__(16) _Float16 As[64 * 32];
  __shared__ __align__(16) _Float16 Bs[64 * 32];
  const int tid = threadIdx.x;
  const int lane = tid & 63, wave = tid >> 6;
  const int wm = (wave >> 1) * 32, wn = (wave & 1) * 32;
  const int srow = tid >> 2, sq = tid & 3;   // staging: row 0..63, 8-elt chunk
  const int mrow = lane & 15, q = lane >> 4; // frag coords
  f32x4 acc[2][2] = {};
  for (int kk = 0; kk < EE; kk += 32) {
    union { int4 v; unsigned short u[8]; } ua, ub;
    ua.v = *(const int4*)(x + (size_t)(m0 + srow) * EE + kk + sq * 8);
    ub.v.x = 0; ub.v.y = 0; ub.v.z = 0; ub.v.w = 0;
    int n = n0 + srow;
    if (n < GG) ub.v = *(const int4*)(wih + (size_t)n * EE + kk + sq * 8);
    f16x8 af, bf;
#pragma unroll
    for (int r = 0; r < 8; ++r) {
      af[r] = (_Float16)bf2f(ua.u[r]);
      bf[r] = (_Float16)bf2f(ub.u[r]);
    }
    __syncthreads();
    *(f16x8*)(As + srow * 32 + sq * 8) = af;
    *(f16x8*)(Bs + srow * 32 + sq * 8) = bf;
    __syncthreads();
    f16x8 a0 = *(const f16x8*)(As + (wm + mrow) * 32 + q * 8);
    f16x8 a1 = *(const f16x8*)(As + (wm + 16 + mrow) * 32 + q * 8);
    f16x8 b0 = *(const f16x8*)(Bs + (wn + mrow) * 32 + q * 8);
    f16x8 b1 = *(const f16x8*)(Bs + (wn + 16 + mrow) * 32 + q * 8);
    acc[0][0] = __builtin_amdgcn_mfma_f32_16x16x32_f16(a0, b0, acc[0][0], 0, 0, 0);
    acc[0][1] = __builtin_amdgcn_mfma_f32_16x16x32_f16(a0, b1, acc[0][1], 0, 0, 0);
    acc[1][0] = __builtin_amdgcn_mfma_f32_16x16x32_f16(a1, b0, acc[1][0], 0, 0, 0);
    acc[1][1] = __builtin_amdgcn_mfma_f32_16x16x32_f16(a1, b1, acc[1][1], 0, 0, 0);
  }
#pragma unroll
  for (int im = 0; im < 2; ++im) {
#pragma unroll
    for (int in = 0; in < 2; ++in) {
      int n = n0 + wn + in * 16 + mrow;
      if (n < GG) {
        float bb = bf2f(bias[n]);
#pragma unroll
        for (int r = 0; r < 4; ++r) {
          int mg = m0 + wm + im * 16 + q * 4 + r;
          gates[((size_t)dir * MM + mg) * GG + n] = f2bf(acc[im][in][r] + bb);
        }
      }
    }
  }
}
#else
__global__ __launch_bounds__(256) void k_gates(
    const unsigned short* __restrict__ x,
    const unsigned short* __restrict__ wih_f, const unsigned short* __restrict__ wih_b,
    const unsigned short* __restrict__ bias_f, const unsigned short* __restrict__ bias_b,
    unsigned short* __restrict__ gates) {
  const int dir = blockIdx.z;
  const unsigned short* wih = dir ? wih_b : wih_f;
  const unsigned short* bias = dir ? bias_b : bias_f;
  const int m0 = blockIdx.x * 64;
  const int n0 = blockIdx.y * 64;
  for (int r = 0; r < 16; ++r) {
    int idx = threadIdx.x + 256 * r;
    int m = m0 + (idx >> 6), n = n0 + (idx & 63);
    if (n >= GG) continue;
    float acc = bf2f(bias[n]);
    const unsigned short* xr = x + (size_t)m * EE;
    const unsigned short* wr = wih + (size_t)n * EE;
    for (int k = 0; k < EE; ++k) acc += bf2f(xr[k]) * bf2f(wr[k]);
    gates[((size_t)dir * MM + m) * GG + n] = f2bf(acc);
  }
}
#endif

// --------------------------------------------------------- LSTM recurrence
// v8. Ledger: streaming family = 667-690 us across v1/v2/v3/v5 (L1-path bound,
// ~3190 cyc/step). v4 proved 256thr+wpe(1,1) => 256-reg grant really held.
// v7b proved 512thr => ~112-128 grant, spilled pinned weights => scratch
// reloads (2.0 ms). v8 balances W across three stores at their pipe BWs:
//   regs: 256 rows (1 row/thread = 100 VGPRs; 100+~45 temps < 256 grant)
//   LDS : 384 rows, chunk-transposed [25][384][8] => conflict-free b128 reads
//         (153.6 KB; HK precedent: >=128 KB static LDS works on gfx950)
//   L2  : 160 rows streamed, chunk-transposed => coalesced 1KB/wave-instr
// Per step: issue ~800-1050 cyc || LDS 1200 cyc || L2 1000 cyc => ~1500-1800.
// Row ownership (uniform algebra): thread t owns rows {t, 256+t, 512+t} and
// t in [224,256) also owns row 544+t (= 768..799). gbuf slots match row ids.
#define REP25(M) M(0) M(1) M(2) M(3) M(4) M(5) M(6) M(7) M(8) M(9) M(10) \
  M(11) M(12) M(13) M(14) M(15) M(16) M(17) M(18) M(19) M(20) M(21) M(22) \
  M(23) M(24)

// chunk body, t < 128: third row from LDS (row 512+t -> ldsw slot 256+t)
#define CHUNKL(n) { \
  i32x4 hc = *(const i32x4*)(hp + (n) * 8); \
  ra0 = dot2acc(i2h2(w##n[0]), i2h2(hc[0]), ra0); \
  ra1 = dot2acc(i2h2(w##n[1]), i2h2(hc[1]), ra1); \
  ra0 = dot2acc(i2h2(w##n[2]), i2h2(hc[2]), ra0); \
  ra1 = dot2acc(i2h2(w##n[3]), i2h2(hc[3]), ra1); \
  i32x4 u1 = *(const i32x4*)(ldsw + (n) * 3072 + t * 8); \
  rb0 = dot2acc(i2h2(u1[0]), i2h2(hc[0]), rb0); \
  rb1 = dot2acc(i2h2(u1[1]), i2h2(hc[1]), rb1); \
  rb0 = dot2acc(i2h2(u1[2]), i2h2(hc[2]), rb0); \
  rb1 = dot2acc(i2h2(u1[3]), i2h2(hc[3]), rb1); \
  i32x4 u2 = *(const i32x4*)(ldsw + 2048 + (n) * 3072 + t * 8); \
  rc0 = dot2acc(i2h2(u2[0]), i2h2(hc[0]), rc0); \
  rc1 = dot2acc(i2h2(u2[1]), i2h2(hc[1]), rc1); \
  rc0 = dot2acc(i2h2(u2[2]), i2h2(hc[2]), rc0); \
  rc1 = dot2acc(i2h2(u2[3]), i2h2(hc[3]), rc1); }

// chunk body, t >= 128: third row streamed; t >= 224 also a fourth row
#define CHUNKG(n) { \
  i32x4 hc = *(const i32x4*)(hp + (n) * 8); \
  ra0 = dot2acc(i2h2(w##n[0]), i2h2(hc[0]), ra0); \
  ra1 = dot2acc(i2h2(w##n[1]), i2h2(hc[1]), ra1); \
  ra0 = dot2acc(i2h2(w##n[2]), i2h2(hc[2]), ra0); \
  ra1 = dot2acc(i2h2(w##n[3]), i2h2(hc[3]), ra1); \
  i32x4 u1 = *(const i32x4*)(ldsw + (n) * 3072 + t * 8); \
  rb0 = dot2acc(i2h2(u1[0]), i2h2(hc[0]), rb0); \
  rb1 = dot2acc(i2h2(u1[1]), i2h2(hc[1]), rb1); \
  rb0 = dot2acc(i2h2(u1[2]), i2h2(hc[2]), rb0); \
  rb1 = dot2acc(i2h2(u1[3]), i2h2(hc[3]), rb1); \
  i32x4 u2 = *(const i32x4*)(strD2 + (size_t)(n) * 1280); \
  rc0 = dot2acc(i2h2(u2[0]), i2h2(hc[0]), rc0); \
  rc1 = dot2acc(i2h2(u2[1]), i2h2(hc[1]), rc1); \
  rc0 = dot2acc(i2h2(u2[2]), i2h2(hc[2]), rc0); \
  rc1 = dot2acc(i2h2(u2[3]), i2h2(hc[3]), rc1); \
  if (has4) { \
    i32x4 u3 = *(const i32x4*)(r3 + (size_t)(n) * 1280); \
    rd0 = dot2acc(i2h2(u3[0]), i2h2(hc[0]), rd0); \
    rd1 = dot2acc(i2h2(u3[1]), i2h2(hc[1]), rd1); \
    rd0 = dot2acc(i2h2(u3[2]), i2h2(hc[2]), rd0); \
    rd1 = dot2acc(i2h2(u3[3]), i2h2(hc[3]), rd1); } }

__global__ __launch_bounds__(256) __attribute__((amdgpu_waves_per_eu(1, 1)))
void k_lstm(
    const unsigned short* __restrict__ gates,
    const _Float16* __restrict__ whh16,
    const int* __restrict__ seq_len,
    unsigned short* __restrict__ h_out) {
  const int b = blockIdx.x & (BB - 1);
  const int dir = blockIdx.x >> 6;
  const int t = threadIdx.x;
  const int L = seq_len[b];
  __shared__ __align__(16) _Float16 ldsw[76800];    // [25][384][8], 153.6 KB
  __shared__ __align__(16) _Float16 hsh[2][HH];     // double-buffered h
  __shared__ float gbuf[GG];
  const _Float16* Wplain  = whh16 + (size_t)dir * 160000;
  const _Float16* ldsTsrc = whh16 + 320000 + (size_t)dir * 76800;
  const _Float16* strD    = whh16 + 473600 + (size_t)dir * 32000;

  // Register row t (100 VGPRs, loaded directly as f16).
  const _Float16* wr = Wplain + (size_t)t * HH;
#define DECLW(n) i32x4 w##n = *(const i32x4*)(wr + (n) * 8);
  REP25(DECLW)
#undef DECLW
#define PINW(n) asm("" : "+v"(w##n));
  REP25(PINW)
#undef PINW

  // Cooperative LDS fill (coalesced both sides: linear copy of ldsT[dir]).
  for (int i = t; i < 9600; i += 256)
    ((i32x4*)ldsw)[i] = ((const i32x4*)ldsTsrc)[i];

  const bool has4 = (t >= 224);
  const _Float16* strD2 = strD + (size_t)((t >= 128) ? (t - 128) : 0) * 8;
  const _Float16* r3    = strD + (size_t)(has4 ? (t - 96) : 0) * 8;

  if (t < HH) { hsh[0][t] = (_Float16)0.0f; hsh[1][t] = (_Float16)0.0f; }
  float c_st = 0.0f, h_st = 0.0f;
  const unsigned short* g0 = gates + ((size_t)dir * MM + (size_t)b * TT) * GG;
  unsigned short* hobase = h_out + (size_t)(dir * BB + b) * TT * HH;
  const int t0 = dir ? (L - 1) : 0;
  float gx0 = bf2f(g0[(size_t)t0 * GG + t]);
  float gx1 = bf2f(g0[(size_t)t0 * GG + 256 + t]);
  float gx2 = bf2f(g0[(size_t)t0 * GG + 512 + t]);
  float gx3 = has4 ? bf2f(g0[(size_t)t0 * GG + 544 + t]) : 0.0f;
  __syncthreads();
#pragma unroll 1
  for (int s = 0; s < L; ++s) {
    const int tt = dir ? (L - 1 - s) : s;
    const int p = s & 1;
    int sn = (s + 1 < L) ? (s + 1) : s;
    int tn = dir ? (L - 1 - sn) : sn;
    float gn0 = bf2f(g0[(size_t)tn * GG + t]);           // prefetch next step
    float gn1 = bf2f(g0[(size_t)tn * GG + 256 + t]);
    float gn2 = bf2f(g0[(size_t)tn * GG + 512 + t]);
    float gn3 = has4 ? bf2f(g0[(size_t)tn * GG + 544 + t]) : 0.0f;
    float ra0 = gx0, ra1 = 0.0f, rb0 = gx1, rb1 = 0.0f;
    float rc0 = gx2, rc1 = 0.0f, rd0 = gx3, rd1 = 0.0f;
    const _Float16* hp = hsh[p];
    if (t < 128) {            // wave-uniform branch (waves 0-1 vs 2-3)
      REP25(CHUNKL)
    } else {
      REP25(CHUNKG)
    }
    gbuf[t] = ra0 + ra1;
    gbuf[256 + t] = rb0 + rb1;
    gbuf[512 + t] = rc0 + rc1;
    if (has4) gbuf[544 + t] = rd0 + rd1;
    gx0 = gn0; gx1 = gn1; gx2 = gn2; gx3 = gn3;
    __syncthreads();                   // gbuf ready
    if (t < HH) {
      float gi = gbuf[t], gf = gbuf[HH + t];
      float gg = gbuf[2 * HH + t], go = gbuf[3 * HH + t];
      float cn = sigf(gf) * c_st + sigf(gi) * tanhfast(gg);
      float hn = sigf(go) * tanhfast(cn);
      c_st = cn; h_st = hn;            // every executed step has tt < L
      hsh[p ^ 1][t] = (_Float16)h_st;
      hobase[(size_t)tt * HH + t] = f2bf(h_st);
    }
    __syncthreads();                   // h(p^1) + gbuf reads done
  }
}
#undef REP25
#undef CHUNKL
#undef CHUNKG

// --------------------------------------------- FC (concat h) + log_softmax
__global__ __launch_bounds__(256) void k_fc(
    const unsigned short* __restrict__ h_out,
    const unsigned short* __restrict__ fc_w, const unsigned short* __restrict__ fc_b,
    float* __restrict__ logits) {
  __shared__ __align__(16) unsigned short hsh[4][2 * HH];
  const int wv = threadIdx.x >> 6, lane = threadIdx.x & 63;
  const int m = blockIdx.x * 4 + wv;  // token = b*TT + t
  if (lane < 25) {
    *(int4*)&hsh[wv][lane * 8] = *(const int4*)(h_out + (size_t)m * HH + lane * 8);
  } else if (lane < 50) {
    *(int4*)&hsh[wv][HH + (lane - 25) * 8] =
        *(const int4*)(h_out + (size_t)MM * HH + (size_t)m * HH + (lane - 25) * 8);
  }
  __syncthreads();
  float s = -3.0e38f;
  if (lane < CC) {
    s = bf2f(fc_b[lane]);
    const unsigned short* wrow = fc_w + lane * 2 * HH;
    for (int jj = 0; jj < 50; ++jj) {
      union { int4 v; unsigned short u[8]; } hw, ww;
      hw.v = *(const int4*)&hsh[wv][jj * 8];
      ww.v = *(const int4*)(wrow + jj * 8);
#pragma unroll
      for (int r = 0; r < 8; ++r) s += bf2f(hw.u[r]) * bf2f(ww.u[r]);
    }
  }
  float mx = s;
#pragma unroll
  for (int off = 32; off > 0; off >>= 1) mx = fmaxf(mx, __shfl_xor(mx, off, 64));
  float ex = (lane < CC) ? __expf(s - mx) : 0.0f;
  float sm = ex;
#pragma unroll
  for (int off = 32; off > 0; off >>= 1) sm += __shfl_xor(sm, off, 64);
  if (lane < CC) logits[(size_t)m * CC + lane] = s - mx - __logf(sm);
}

// ----------------------------------------------------------------- CRF NLL
__global__ __launch_bounds__(64) void k_crf(
    const float* __restrict__ logits, const int* __restrict__ target,
    const int* __restrict__ seq_len, const unsigned short* __restrict__ trans,
    const unsigned short* __restrict__ startv, const unsigned short* __restrict__ endv,
    float* __restrict__ loss_b) {
  const int b = blockIdx.x, lane = threadIdx.x;
  const int L = seq_len[b];
  const int* tg = target + b * TT;
  const float* lg = logits + (size_t)b * TT * CC;
  float tcol[CC];
#pragma unroll
  for (int i = 0; i < CC; ++i) tcol[i] = (lane < CC) ? bf2f(trans[i * CC + lane]) : 0.0f;
  float g = 0.0f;
  for (int t = lane; t < TT; t += 64) {
    if (t < L) {
      g += lg[t * CC + tg[t]];
      if (t >= 1) g += bf2f(trans[tg[t - 1] * CC + tg[t]]);
    }
  }
#pragma unroll
  for (int off = 32; off > 0; off >>= 1) g += __shfl_xor(g, off, 64);
  float alpha = (lane < CC) ? (bf2f(startv[lane]) + lg[lane]) : -3.0e38f;
  for (int t = 1; t < L; ++t) {
    float e = (lane < CC) ? lg[t * CC + lane] : 0.0f;
    float sc[CC];
#pragma unroll
    for (int i = 0; i < CC; ++i) sc[i] = __shfl(alpha, i, 64) + tcol[i];
    float mx = sc[0];
#pragma unroll
    for (int i = 1; i < CC; ++i) mx = fmaxf(mx, sc[i]);
    float sm = 0.0f;
#pragma unroll
    for (int i = 0; i < CC; ++i) sm += __expf(sc[i] - mx);
    float na = mx + __logf(sm) + e;
    if (lane < CC) alpha = na;
  }
  float v = (lane < CC) ? (alpha + bf2f(endv[lane])) : -3.0e38f;
  float mx = v;
#pragma unroll
  for (int off = 32; off > 0; off >>= 1) mx = fmaxf(mx, __shfl_xor(mx, off, 64));
  float ex = (lane < CC) ? __expf(v - mx) : 0.0f;
#pragma unroll
  for (int off = 32; off > 0; off >>= 1) ex += __shfl_xor(ex, off, 64);
  if (lane == 0) {
    float logZ = mx + __logf(ex);
    float gold = g + bf2f(startv[tg[0]]) + bf2f(endv[tg[L - 1]]);
    loss_b[b] = logZ - gold;
  }
}

// ------------------------------------------------------------- mean over B
__global__ __launch_bounds__(64) void k_mean(const float* __restrict__ loss_b,
                                             unsigned int* __restrict__ out) {
  float v = loss_b[threadIdx.x];
#pragma unroll
  for (int off = 32; off > 0; off >>= 1) v += __shfl_xor(v, off, 64);
  if (threadIdx.x == 0) {
    float mean = v * (1.0f / BB);
    unsigned int lo = (unsigned int)f2bf(mean);
    unsigned int hi = __float_as_uint(mean) >> 16;
    out[0] = (hi << 16) | lo;
  }
}

// ---------------------------------------------------------------- launcher
extern "C" void kernel_launch(void* const* d_in, const int* in_sizes, int n_in,
                              void* d_out, int out_size, void* d_ws, size_t ws_size,
                              hipStream_t stream) {
  const int* words   = (const int*)d_in[0];
  const int* seq_len = (const int*)d_in[1];
  const int* target  = (const int*)d_in[2];

  char* ws = (char*)d_ws;
  const size_t x_off      = 0;                       // 32768*256*2   = 16,777,216
  const size_t gates_off  = x_off + 16777216;        // 2*32768*800*2 = 104,857,600
  const size_t h_off      = gates_off + 104857600;   // 2*64*512*200*2 = 26,214,400
  const size_t logits_off = h_off + 26214400;        // 32768*20*4    = 2,621,440
  const size_t loss_off   = logits_off + 2621440;    // 64*4 (+pad to 256)
  const size_t cvt_off    = loss_off + 256;          // 8,932,172 bf16 elements
  unsigned short* x      = (unsigned short*)(ws + x_off);
  unsigned short* gatesb = (unsigned short*)(ws + gates_off);
  unsigned short* h_out  = (unsigned short*)(ws + h_off);
  float* logits          = (float*)(ws + logits_off);
  float* loss_b          = (float*)(ws + loss_off);
  unsigned short* wcvt   = (unsigned short*)(ws + cvt_off);
  // f16 W_hh views (plain 640,000 B + ldsT 307,200 B + strT 128,000 B =
  // 1,075,200 B) OVERLAY the logits region (2.6 MB): written by k_convert,
  // read only by k_lstm; k_fc (which writes logits) runs strictly after
  // k_lstm on the same stream -> lifetime-disjoint, no extra ws needed.
  _Float16* whh16 = (_Float16*)(ws + logits_off);

  // converted-tensor pointers (element offsets = cvt_cum prefix sums)
  unsigned short* etab_c  = wcvt + 0;
  unsigned short* gamma_c = wcvt + 8192000;
  unsigned short* beta_c  = wcvt + 8192256;
  unsigned short* wih_f_c = wcvt + 8192512;
  unsigned short* b_f_c   = wcvt + 8557312;
  unsigned short* wih_b_c = wcvt + 8558112;
  unsigned short* b_b_c   = wcvt + 8922912;
  unsigned short* fc_w_c  = wcvt + 8923712;
  unsigned short* fc_b_c  = wcvt + 8931712;
  unsigned short* trans_c = wcvt + 8931732;
  unsigned short* start_c = wcvt + 8932132;
  unsigned short* end_c   = wcvt + 8932152;

  CvtArgs ca;
  for (int i = 0; i < NSEG; ++i) ca.src[i] = d_in[3 + i];
  const int total_cvt = 8932172;
  k_convert<<<(total_cvt + 1023) / 1024, 256, 0, stream>>>(ca, wcvt, whh16);

  k_embed_ln<<<MM, 256, 0, stream>>>(words, etab_c, gamma_c, beta_c, x);
  k_gates<<<dim3(MM / 64, 13, 2), 256, 0, stream>>>(x, wih_f_c, wih_b_c, b_f_c, b_b_c, gatesb);
  k_lstm<<<128, 256, 0, stream>>>(gatesb, whh16, seq_len, h_out);
  k_fc<<<MM / 4, 256, 0, stream>>>(h_out, fc_w_c, fc_b_c, logits);
  k_crf<<<BB, 64, 0, stream>>>(logits, target, seq_len, trans_c, start_c, end_c, loss_b);
  k_mean<<<1, 64, 0, stream>>>(loss_b, (unsigned int*)d_out);
}

// Round 9
// 2295.982 us; speedup vs baseline: 1.3735x; 1.3735x over previous
//
#include <hip/hip_runtime.h>

#define TT 512
#define BB 64
#define EE 256
#define HH 200
#define GG 800
#define CC 20
#define MM (BB * TT)  // 32768 tokens

// Collision-proof names (HIP's hip_vector_types.h defines short8/float8/etc).
typedef _Float16 f16x8 __attribute__((ext_vector_type(8)));
typedef float    f32x4 __attribute__((ext_vector_type(4)));
typedef _Float16 f16x2 __attribute__((ext_vector_type(2)));
typedef int      i32x4 __attribute__((ext_vector_type(4)));

#if __has_builtin(__builtin_amdgcn_mfma_f32_16x16x32_f16)
#define HAVE_MFMA_F16 1
#else
#define HAVE_MFMA_F16 0
#endif

__device__ __forceinline__ float bf2f(unsigned short u) {
  return __uint_as_float(((unsigned int)u) << 16);
}
__device__ __forceinline__ unsigned short f2bf(float f) {
  unsigned int u = __float_as_uint(f);
  return (unsigned short)((u + 0x7fffu + ((u >> 16) & 1u)) >> 16);
}
__device__ __forceinline__ float sigf(float x) { return 1.0f / (1.0f + __expf(-x)); }
__device__ __forceinline__ float tanhfast(float x) {
  return 1.0f - 2.0f / (__expf(2.0f * x) + 1.0f);
}
__device__ __forceinline__ f16x2 i2h2(int i) {
  union { int i; f16x2 h; } u; u.i = i; return u.h;
}
__device__ __forceinline__ float dot2acc(f16x2 a, f16x2 b, float c) {
#if __has_builtin(__builtin_amdgcn_fdot2)
  return __builtin_amdgcn_fdot2(a, b, c, false);
#else
  return c + (float)a[0] * (float)b[0] + (float)a[1] * (float)b[1];
#endif
}

// --------------------------------------------------- input dtype normalizer
// Emits, besides the bf16 copies, three f16 views of W_hh for k_lstm:
//   plain [2][800][200]                     (register half-rows, rows 0..255)
//   ldsT  [2][25][320][8]  rows 256..447 (slot row-256) and 512..639 (row-320)
//   strT  [2][25][224][8]  rows 448..511 (slot row-448) and 640..799 (row-576)
// chunk-transposed so both the LDS fill and the streamed reads coalesce.
#define NSEG 14
struct CvtArgs { const void* src[NSEG]; };
__constant__ const int cvt_cum[NSEG + 1] = {
    0, 8192000, 8192256, 8192512, 8397312, 8557312, 8558112,
    8762912, 8922912, 8923712, 8931712, 8931732, 8932132, 8932152, 8932172};

__global__ __launch_bounds__(256) void k_convert(CvtArgs a,
                                                 unsigned short* __restrict__ dst,
                                                 _Float16* __restrict__ whh16) {
  const bool f32mode = (((const unsigned int*)a.src[1])[0] == 0x3F800000u);
  int gi0 = (blockIdx.x * 256 + threadIdx.x) * 4;
#pragma unroll
  for (int r = 0; r < 4; ++r) {
    int gi = gi0 + r;
    if (gi >= cvt_cum[NSEG]) return;
    int seg = 0;
#pragma unroll
    for (int s = 1; s < NSEG; ++s) seg += (gi >= cvt_cum[s]) ? 1 : 0;
    int local = gi - cvt_cum[seg];
    unsigned short v;
    if (f32mode) v = f2bf(((const float*)a.src[seg])[local]);
    else         v = ((const unsigned short*)a.src[seg])[local];
    dst[gi] = v;
    if (seg == 4 || seg == 7) {
      int dir = (seg == 7) ? 1 : 0;
      int row = local / 200, col = local - row * 200;
      _Float16 hv = (_Float16)bf2f(v);
      whh16[dir * 160000 + local] = hv;
      int c = col >> 3, e = col & 7;
      if (row >= 256 && row < 448)
        whh16[320000 + dir * 64000 + c * 2560 + (row - 256) * 8 + e] = hv;
      else if (row >= 512 && row < 640)
        whh16[320000 + dir * 64000 + c * 2560 + (row - 320) * 8 + e] = hv;
      else if (row >= 448 && row < 512)
        whh16[448000 + dir * 44800 + c * 1792 + (row - 448) * 8 + e] = hv;
      else if (row >= 640)
        whh16[448000 + dir * 44800 + c * 1792 + (row - 576) * 8 + e] = hv;
    }
  }
}

// ---------------------------------------------------------------- embed + LN
__global__ __launch_bounds__(256) void k_embed_ln(
    const int* __restrict__ words, const unsigned short* __restrict__ etab,
    const unsigned short* __restrict__ gamma, const unsigned short* __restrict__ beta,
    unsigned short* __restrict__ x) {
  int m = blockIdx.x;      // token = b*TT + t
  int e = threadIdx.x;     // 0..255
  int w = words[m];
  float v = bf2f(etab[(size_t)w * EE + e]);
  float s = v, ss = v * v;
#pragma unroll
  for (int off = 32; off > 0; off >>= 1) {
    s += __shfl_xor(s, off, 64);
    ss += __shfl_xor(ss, off, 64);
  }
  __shared__ float red[2][4];
  int wv = e >> 6;
  if ((e & 63) == 0) { red[0][wv] = s; red[1][wv] = ss; }
  __syncthreads();
  float S = red[0][0] + red[0][1] + red[0][2] + red[0][3];
  float SS = red[1][0] + red[1][1] + red[1][2] + red[1][3];
  float mu = S * (1.0f / EE);
  float var = fmaxf(SS * (1.0f / EE) - mu * mu, 0.0f);
  float nrm = (v - mu) * rsqrtf(var + 1e-5f) * bf2f(gamma[e]) + bf2f(beta[e]);
  x[(size_t)m * EE + e] = f2bf(nrm);
}

// ------------------------------------------- gates_x = x @ W_ih^T + b
#if HAVE_MFMA_F16
__global__ __launch_bounds__(256) void k_gates(
    const unsigned short* __restrict__ x,
    const unsigned short* __restrict__ wih_f, const unsigned short* __restrict__ wih_b,
    const unsigned short* __restrict__ bias_f, const unsigned short* __restrict__ bias_b,
    unsigned short* __restrict__ gates) {
  const int dir = blockIdx.z;
  const unsigned short* wih = dir ? wih_b : wih_f;
  const unsigned short* bias = dir ? bias_b : bias_f;
  const int m0 = blockIdx.x * 64;
  const int n0 = blockIdx.y * 64;
  __shared__ __align__(16) _Float16 As[64 * 32];
  __shared__ __align__(16) _Float16 Bs[64 * 32];
  const int tid = threadIdx.x;
  const int lane = tid & 63, wave = tid >> 6;
  const int wm = (wave >> 1) * 32, wn = (wave & 1) * 32;
  const int srow = tid >> 2, sq = tid & 3;   // staging: row 0..63, 8-elt chunk
  const int mrow = lane & 15, q = lane >> 4; // frag coords
  f32x4 acc[2][2] = {};
  for (int kk = 0; kk < EE; kk += 32) {
    union { int4 v; unsigned short u[8]; } ua, ub;
    ua.v = *(const int4*)(x + (size_t)(m0 + srow) * EE + kk + sq * 8);
    ub.v.x = 0; ub.v.y = 0; ub.v.z = 0; ub.v.w = 0;
    int n = n0 + srow;
    if (n < GG) ub.v = *(const int4*)(wih + (size_t)n * EE + kk + sq * 8);
    f16x8 af, bf;
#pragma unroll
    for (int r = 0; r < 8; ++r) {
      af[r] = (_Float16)bf2f(ua.u[r]);
      bf[r] = (_Float16)bf2f(ub.u[r]);
    }
    __syncthreads();
    *(f16x8*)(As + srow * 32 + sq * 8) = af;
    *(f16x8*)(Bs + srow * 32 + sq * 8) = bf;
    __syncthreads();
    f16x8 a0 = *(const f16x8*)(As + (wm + mrow) * 32 + q * 8);
    f16x8 a1 = *(const f16x8*)(As + (wm + 16 + mrow) * 32 + q * 8);
    f16x8 b0 = *(const f16x8*)(Bs + (wn + mrow) * 32 + q * 8);
    f16x8 b1 = *(const f16x8*)(Bs + (wn + 16 + mrow) * 32 + q * 8);
    acc[0][0] = __builtin_amdgcn_mfma_f32_16x16x32_f16(a0, b0, acc[0][0], 0, 0, 0);
    acc[0][1] = __builtin_amdgcn_mfma_f32_16x16x32_f16(a0, b1, acc[0][1], 0, 0, 0);
    acc[1][0] = __builtin_amdgcn_mfma_f32_16x16x32_f16(a1, b0, acc[1][0], 0, 0, 0);
    acc[1][1] = __builtin_amdgcn_mfma_f32_16x16x32_f16(a1, b1, acc[1][1], 0, 0, 0);
  }
#pragma unroll
  for (int im = 0; im < 2; ++im) {
#pragma unroll
    for (int in = 0; in < 2; ++in) {
      int n = n0 + wn + in * 16 + mrow;
      if (n < GG) {
        float bb = bf2f(bias[n]);
#pragma unroll
        for (int r = 0; r < 4; ++r) {
          int mg = m0 + wm + im * 16 + q * 4 + r;
          gates[((size_t)dir * MM + mg) * GG + n] = f2bf(acc[im][in][r] + bb);
        }
      }
    }
  }
}
#else
__global__ __launch_bounds__(256) void k_gates(
    const unsigned short* __restrict__ x,
    const unsigned short* __restrict__ wih_f, const unsigned short* __restrict__ wih_b,
    const unsigned short* __restrict__ bias_f, const unsigned short* __restrict__ bias_b,
    unsigned short* __restrict__ gates) {
  const int dir = blockIdx.z;
  const unsigned short* wih = dir ? wih_b : wih_f;
  const unsigned short* bias = dir ? bias_b : bias_f;
  const int m0 = blockIdx.x * 64;
  const int n0 = blockIdx.y * 64;
  for (int r = 0; r < 16; ++r) {
    int idx = threadIdx.x + 256 * r;
    int m = m0 + (idx >> 6), n = n0 + (idx & 63);
    if (n >= GG) continue;
    float acc = bf2f(bias[n]);
    const unsigned short* xr = x + (size_t)m * EE;
    const unsigned short* wr = wih + (size_t)n * EE;
    for (int k = 0; k < EE; ++k) acc += bf2f(xr[k]) * bf2f(wr[k]);
    gates[((size_t)dir * MM + m) * GG + n] = f2bf(acc);
  }
}
#endif

// --------------------------------------------------------- LSTM recurrence
// v9. Ledger: baseline streaming (v1/v2/v3/v5) = 680us = aggregate-L2-BW
// bound (~31 TB/s). v8 (256thr+wpe(1,1)+157KB LDS) = 1 wave/SIMD -> latency
// collapse. v9: 512 threads (8 waves, 2/SIMD for hiding, grant ~112), each
// thread owns a HALF-row (100 f16 = 52 VGPRs, fits unlike v7b's 100+28).
//   regs: rows 0..255   (thread t: row=t&255, half=t>>8 -> wave-uniform)
//   LDS : rows 256..447 & 512..639 (320 rows, 128KB, chunk-transposed)
//   L2  : rows 448..511 & 640..799 (224 rows, 89.6KB/step = 3.6x less L2)
// Each thread handles 3 half-rows (+1 for r<32), SAME half -> the 13 h-chunk
// broadcast reads are shared across all sources. All branch boundaries are
// multiples of 64 -> wave-uniform variants. 2 barriers/step.
#define REP13(M) M(0) M(1) M(2) M(3) M(4) M(5) M(6) M(7) M(8) M(9) M(10) \
  M(11) M(12)
#define REP12(M) M(0) M(1) M(2) M(3) M(4) M(5) M(6) M(7) M(8) M(9) M(10) \
  M(11)

#define DOT4(P, V) \
  P##0 = dot2acc(i2h2((V)[0]), i2h2(hc[0]), P##0); \
  P##1 = dot2acc(i2h2((V)[1]), i2h2(hc[1]), P##1); \
  P##0 = dot2acc(i2h2((V)[2]), i2h2(hc[2]), P##0); \
  P##1 = dot2acc(i2h2((V)[3]), i2h2(hc[3]), P##1);

// variant A (r<128): h1 LDS, h2 LDS, h3 (r<32) streamed
#define CHA(n) { \
  i32x4 hc = *(const i32x4*)(hpb + (n) * 8); \
  i32x4 u1 = *(const i32x4*)(lds1p + (n) * 2560); \
  i32x4 u2 = *(const i32x4*)(lds1p + 1536 + (n) * 2560); \
  DOT4(a, w##n) DOT4(b, u1) DOT4(c, u2) \
  if (has3) { \
    i32x4 u3 = *(const i32x4*)(g3p + (n) * 1792); \
    DOT4(d, u3) } }

// variant B (128<=r<192): h1 LDS, h2 streamed
#define CHB(n) { \
  i32x4 hc = *(const i32x4*)(hpb + (n) * 8); \
  i32x4 u1 = *(const i32x4*)(lds1p + (n) * 2560); \
  i32x4 u2 = *(const i32x4*)(g2p + (n) * 1792); \
  DOT4(a, w##n) DOT4(b, u1) DOT4(c, u2) }

// variant C (r>=192): h1 streamed, h2 streamed
#define CHC(n) { \
  i32x4 hc = *(const i32x4*)(hpb + (n) * 8); \
  i32x4 u1 = *(const i32x4*)(g1p + (n) * 1792); \
  i32x4 u2 = *(const i32x4*)(g2p + (n) * 1792); \
  DOT4(a, w##n) DOT4(b, u1) DOT4(c, u2) }

__global__ __launch_bounds__(512) void k_lstm(
    const unsigned short* __restrict__ gates,
    const _Float16* __restrict__ whh16,
    const int* __restrict__ seq_len,
    unsigned short* __restrict__ h_out) {
  const int b = blockIdx.x & (BB - 1);
  const int dir = blockIdx.x >> 6;
  const int t = threadIdx.x;
  const int r = t & 255;          // row-within-group
  const int half = t >> 8;        // 0: cols 0..95 (12 chunks), 1: 96..199 (13)
  const int L = seq_len[b];
  __shared__ __align__(16) _Float16 ldsw[64000];  // [25][320][8] = 128 KB
  __shared__ __align__(16) _Float16 hsh[2][208];  // double-buffered h
  __shared__ float gpA[GG];                       // half-0 partials (+gx)
  __shared__ float gpB[GG];                       // half-1 partials
  const _Float16* Wplain  = whh16 + (size_t)dir * 160000;
  const _Float16* ldsTsrc = whh16 + 320000 + (size_t)dir * 64000;
  const _Float16* strD    = whh16 + 448000 + (size_t)dir * 44800;

  // Register half-row: row r, my half. 13 i32x4 (52 VGPRs); chunk 12 is
  // meaningful only for half==1, harmless in-row read for half==0.
  const _Float16* wreg = Wplain + (size_t)r * 200 + half * 96;
#define DECLW(n) i32x4 w##n = *(const i32x4*)(wreg + (n) * 8);
  REP13(DECLW)
#undef DECLW
#define PINW(n) asm("" : "+v"(w##n));
  REP13(PINW)
#undef PINW

  // Cooperative LDS fill (linear, coalesced both sides).
  for (int i = t; i < 8000; i += 512)
    ((i32x4*)ldsw)[i] = ((const i32x4*)ldsTsrc)[i];

  const bool has3 = (r < 32);
  const _Float16* lds1p = ldsw + half * 12 * 2560 + r * 8;          // h1 LDS
  const _Float16* strDh = strD + half * 12 * 1792;
  const _Float16* g1p = strDh + (size_t)((r >= 192) ? (r - 192) : 0) * 8;
  const _Float16* g2p = strDh + 512 + (size_t)((r >= 128) ? (r - 128) : 0) * 8;
  const _Float16* g3p = strDh + 1536 + (size_t)(has3 ? r : 0) * 8;

  if (t < 208) { hsh[0][t] = (_Float16)0.0f; hsh[1][t] = (_Float16)0.0f; }
  float c_st = 0.0f, h_st = 0.0f;
  const unsigned short* g0 = gates + ((size_t)dir * MM + (size_t)b * TT) * GG;
  unsigned short* hobase = h_out + (size_t)(dir * BB + b) * TT * HH;
  const int t0 = dir ? (L - 1) : 0;
  float gx0 = 0.0f, gx1 = 0.0f, gx2 = 0.0f, gx3 = 0.0f;
  if (!half) {                    // gate-x added once per row, via half-0
    gx0 = bf2f(g0[(size_t)t0 * GG + r]);
    gx1 = bf2f(g0[(size_t)t0 * GG + 256 + r]);
    gx2 = bf2f(g0[(size_t)t0 * GG + 512 + r]);
    gx3 = has3 ? bf2f(g0[(size_t)t0 * GG + 768 + r]) : 0.0f;
  }
  __syncthreads();
#pragma unroll 1
  for (int s = 0; s < L; ++s) {
    const int tt = dir ? (L - 1 - s) : s;
    const int p = s & 1;
    int sn = (s + 1 < L) ? (s + 1) : s;
    int tn = dir ? (L - 1 - sn) : sn;
    float gn0 = 0.0f, gn1 = 0.0f, gn2 = 0.0f, gn3 = 0.0f;
    if (!half) {                  // prefetch next step's gate-x
      gn0 = bf2f(g0[(size_t)tn * GG + r]);
      gn1 = bf2f(g0[(size_t)tn * GG + 256 + r]);
      gn2 = bf2f(g0[(size_t)tn * GG + 512 + r]);
      gn3 = has3 ? bf2f(g0[(size_t)tn * GG + 768 + r]) : 0.0f;
    }
    float a0 = gx0, a1 = 0.0f, b0 = gx1, b1 = 0.0f;
    float c0 = gx2, c1 = 0.0f, d0 = gx3, d1 = 0.0f;
    const _Float16* hpb = hsh[p] + half * 96;
    if (r < 128) {
      REP12(CHA)
      if (half) { CHA(12) }
    } else if (r < 192) {
      REP12(CHB)
      if (half) { CHB(12) }
    } else {
      REP12(CHC)
      if (half) { CHC(12) }
    }
    float* gp = half ? gpB : gpA;
    gp[r] = a0 + a1;
    gp[256 + r] = b0 + b1;
    gp[512 + r] = c0 + c1;
    if (has3) gp[768 + r] = d0 + d1;
    gx0 = gn0; gx1 = gn1; gx2 = gn2; gx3 = gn3;
    __syncthreads();                   // partials ready
    if (t < HH) {
      float gi = gpA[t] + gpB[t];
      float gf = gpA[HH + t] + gpB[HH + t];
      float gg = gpA[2 * HH + t] + gpB[2 * HH + t];
      float go = gpA[3 * HH + t] + gpB[3 * HH + t];
      float cn = sigf(gf) * c_st + sigf(gi) * tanhfast(gg);
      float hn = sigf(go) * tanhfast(cn);
      c_st = cn; h_st = hn;            // every executed step has tt < L
      hsh[p ^ 1][t] = (_Float16)h_st;
      hobase[(size_t)tt * HH + t] = f2bf(h_st);
    }
    __syncthreads();                   // h(p^1) + partial reads done
  }
}
#undef REP13
#undef REP12
#undef DOT4
#undef CHA
#undef CHB
#undef CHC

// --------------------------------------------- FC (concat h) + log_softmax
__global__ __launch_bounds__(256) void k_fc(
    const unsigned short* __restrict__ h_out,
    const unsigned short* __restrict__ fc_w, const unsigned short* __restrict__ fc_b,
    float* __restrict__ logits) {
  __shared__ __align__(16) unsigned short hsh[4][2 * HH];
  const int wv = threadIdx.x >> 6, lane = threadIdx.x & 63;
  const int m = blockIdx.x * 4 + wv;  // token = b*TT + t
  if (lane < 25) {
    *(int4*)&hsh[wv][lane * 8] = *(const int4*)(h_out + (size_t)m * HH + lane * 8);
  } else if (lane < 50) {
    *(int4*)&hsh[wv][HH + (lane - 25) * 8] =
        *(const int4*)(h_out + (size_t)MM * HH + (size_t)m * HH + (lane - 25) * 8);
  }
  __syncthreads();
  float s = -3.0e38f;
  if (lane < CC) {
    s = bf2f(fc_b[lane]);
    const unsigned short* wrow = fc_w + lane * 2 * HH;
    for (int jj = 0; jj < 50; ++jj) {
      union { int4 v; unsigned short u[8]; } hw, ww;
      hw.v = *(const int4*)&hsh[wv][jj * 8];
      ww.v = *(const int4*)(wrow + jj * 8);
#pragma unroll
      for (int r = 0; r < 8; ++r) s += bf2f(hw.u[r]) * bf2f(ww.u[r]);
    }
  }
  float mx = s;
#pragma unroll
  for (int off = 32; off > 0; off >>= 1) mx = fmaxf(mx, __shfl_xor(mx, off, 64));
  float ex = (lane < CC) ? __expf(s - mx) : 0.0f;
  float sm = ex;
#pragma unroll
  for (int off = 32; off > 0; off >>= 1) sm += __shfl_xor(sm, off, 64);
  if (lane < CC) logits[(size_t)m * CC + lane] = s - mx - __logf(sm);
}

// ----------------------------------------------------------------- CRF NLL
__global__ __launch_bounds__(64) void k_crf(
    const float* __restrict__ logits, const int* __restrict__ target,
    const int* __restrict__ seq_len, const unsigned short* __restrict__ trans,
    const unsigned short* __restrict__ startv, const unsigned short* __restrict__ endv,
    float* __restrict__ loss_b) {
  const int b = blockIdx.x, lane = threadIdx.x;
  const int L = seq_len[b];
  const int* tg = target + b * TT;
  const float* lg = logits + (size_t)b * TT * CC;
  float tcol[CC];
#pragma unroll
  for (int i = 0; i < CC; ++i) tcol[i] = (lane < CC) ? bf2f(trans[i * CC + lane]) : 0.0f;
  float g = 0.0f;
  for (int t = lane; t < TT; t += 64) {
    if (t < L) {
      g += lg[t * CC + tg[t]];
      if (t >= 1) g += bf2f(trans[tg[t - 1] * CC + tg[t]]);
    }
  }
#pragma unroll
  for (int off = 32; off > 0; off >>= 1) g += __shfl_xor(g, off, 64);
  float alpha = (lane < CC) ? (bf2f(startv[lane]) + lg[lane]) : -3.0e38f;
  for (int t = 1; t < L; ++t) {
    float e = (lane < CC) ? lg[t * CC + lane] : 0.0f;
    float sc[CC];
#pragma unroll
    for (int i = 0; i < CC; ++i) sc[i] = __shfl(alpha, i, 64) + tcol[i];
    float mx = sc[0];
#pragma unroll
    for (int i = 1; i < CC; ++i) mx = fmaxf(mx, sc[i]);
    float sm = 0.0f;
#pragma unroll
    for (int i = 0; i < CC; ++i) sm += __expf(sc[i] - mx);
    float na = mx + __logf(sm) + e;
    if (lane < CC) alpha = na;
  }
  float v = (lane < CC) ? (alpha + bf2f(endv[lane])) : -3.0e38f;
  float mx = v;
#pragma unroll
  for (int off = 32; off > 0; off >>= 1) mx = fmaxf(mx, __shfl_xor(mx, off, 64));
  float ex = (lane < CC) ? __expf(v - mx) : 0.0f;
#pragma unroll
  for (int off = 32; off > 0; off >>= 1) ex += __shfl_xor(ex, off, 64);
  if (lane == 0) {
    float logZ = mx + __logf(ex);
    float gold = g + bf2f(startv[tg[0]]) + bf2f(endv[tg[L - 1]]);
    loss_b[b] = logZ - gold;
  }
}

// ------------------------------------------------------------- mean over B
__global__ __launch_bounds__(64) void k_mean(const float* __restrict__ loss_b,
                                             unsigned int* __restrict__ out) {
  float v = loss_b[threadIdx.x];
#pragma unroll
  for (int off = 32; off > 0; off >>= 1) v += __shfl_xor(v, off, 64);
  if (threadIdx.x == 0) {
    float mean = v * (1.0f / BB);
    unsigned int lo = (unsigned int)f2bf(mean);
    unsigned int hi = __float_as_uint(mean) >> 16;
    out[0] = (hi << 16) | lo;
  }
}

// ---------------------------------------------------------------- launcher
extern "C" void kernel_launch(void* const* d_in, const int* in_sizes, int n_in,
                              void* d_out, int out_size, void* d_ws, size_t ws_size,
                              hipStream_t stream) {
  const int* words   = (const int*)d_in[0];
  const int* seq_len = (const int*)d_in[1];
  const int* target  = (const int*)d_in[2];

  char* ws = (char*)d_ws;
  const size_t x_off      = 0;                       // 32768*256*2   = 16,777,216
  const size_t gates_off  = x_off + 16777216;        // 2*32768*800*2 = 104,857,600
  const size_t h_off      = gates_off + 104857600;   // 2*64*512*200*2 = 26,214,400
  const size_t logits_off = h_off + 26214400;        // 32768*20*4    = 2,621,440
  const size_t loss_off   = logits_off + 2621440;    // 64*4 (+pad to 256)
  const size_t cvt_off    = loss_off + 256;          // 8,932,172 bf16 elements
  unsigned short* x      = (unsigned short*)(ws + x_off);
  unsigned short* gatesb = (unsigned short*)(ws + gates_off);
  unsigned short* h_out  = (unsigned short*)(ws + h_off);
  float* logits          = (float*)(ws + logits_off);
  float* loss_b          = (float*)(ws + loss_off);
  unsigned short* wcvt   = (unsigned short*)(ws + cvt_off);
  // f16 W_hh views (plain 640,000 + ldsT 256,000 + strT 179,200 B =
  // 1,075,200 B) OVERLAY the logits region (2.6 MB): written by k_convert,
  // read only by k_lstm; k_fc (which writes logits) runs strictly after
  // k_lstm on the same stream -> lifetime-disjoint, no extra ws needed.
  _Float16* whh16 = (_Float16*)(ws + logits_off);

  // converted-tensor pointers (element offsets = cvt_cum prefix sums)
  unsigned short* etab_c  = wcvt + 0;
  unsigned short* gamma_c = wcvt + 8192000;
  unsigned short* beta_c  = wcvt + 8192256;
  unsigned short* wih_f_c = wcvt + 8192512;
  unsigned short* b_f_c   = wcvt + 8557312;
  unsigned short* wih_b_c = wcvt + 8558112;
  unsigned short* b_b_c   = wcvt + 8922912;
  unsigned short* fc_w_c  = wcvt + 8923712;
  unsigned short* fc_b_c  = wcvt + 8931712;
  unsigned short* trans_c = wcvt + 8931732;
  unsigned short* start_c = wcvt + 8932132;
  unsigned short* end_c   = wcvt + 8932152;

  CvtArgs ca;
  for (int i = 0; i < NSEG; ++i) ca.src[i] = d_in[3 + i];
  const int total_cvt = 8932172;
  k_convert<<<(total_cvt + 1023) / 1024, 256, 0, stream>>>(ca, wcvt, whh16);

  k_embed_ln<<<MM, 256, 0, stream>>>(words, etab_c, gamma_c, beta_c, x);
  k_gates<<<dim3(MM / 64, 13, 2), 256, 0, stream>>>(x, wih_f_c, wih_b_c, b_f_c, b_b_c, gatesb);
  k_lstm<<<128, 512, 0, stream>>>(gatesb, whh16, seq_len, h_out);
  k_fc<<<MM / 4, 256, 0, stream>>>(h_out, fc_w_c, fc_b_c, logits);
  k_crf<<<BB, 64, 0, stream>>>(logits, target, seq_len, trans_c, start_c, end_c, loss_b);
  k_mean<<<1, 64, 0, stream>>>(loss_b, (unsigned int*)d_out);
}